// Round 7
// baseline (876.385 us; speedup 1.0000x reference)
//
#include <hip/hip_runtime.h>

#define TT 4
#define RR 8
#define NH 8
#define DKK 32

typedef float floatx4 __attribute__((ext_vector_type(4)));
typedef __bf16 bf16x8 __attribute__((ext_vector_type(8)));

__device__ __forceinline__ float us2f(unsigned short s){
    union{unsigned int u; float f;} x; x.u = ((unsigned int)s) << 16; return x.f;
}
__device__ __forceinline__ float lo2f(unsigned int u){
    union{unsigned int x; float f;} a; a.x = u << 16; return a.f;
}
__device__ __forceinline__ float hi2f(unsigned int u){
    union{unsigned int x; float f;} a; a.x = u & 0xffff0000u; return a.f;
}
__device__ __forceinline__ unsigned short f2us(float f){
    union{float f; unsigned int u;} x; x.f = f;
    unsigned int u = x.u;
    unsigned int r = (u + 0x7fffu + ((u >> 16) & 1u)) >> 16;   // RNE bf16
    return (unsigned short)r;
}
__device__ __forceinline__ float ldf(const void* p, int i, int isf32){
    return isf32 ? ((const float*)p)[i] : us2f(((const unsigned short*)p)[i]);
}
__device__ __forceinline__ float4 ldf4(const void* p, int i, int isf32){  // i % 4 == 0
    if (isf32) return *reinterpret_cast<const float4*>((const float*)p + i);
    uint2 u = *reinterpret_cast<const uint2*>((const unsigned short*)p + i);
    float4 r; r.x = lo2f(u.x); r.y = hi2f(u.x); r.z = lo2f(u.y); r.w = hi2f(u.y);
    return r;
}
__device__ __forceinline__ const int* sel3(const int* a, const int* b, const int* c, int s){
    return (s == 0) ? a : (s == 1) ? b : c;
}
__device__ __forceinline__ int sw32(int row, int g){
    return row * 32 + ((g ^ (row >> 2)) & 3) * 8;
}
// dot of 8 bf16 pairs held in two uint4 (packed 2xbf16 per uint)
__device__ __forceinline__ float dbb(uint4 a, uint4 b){
    return lo2f(a.x)*lo2f(b.x) + hi2f(a.x)*hi2f(b.x)
         + lo2f(a.y)*lo2f(b.y) + hi2f(a.y)*hi2f(b.y)
         + lo2f(a.z)*lo2f(b.z) + hi2f(a.z)*hi2f(b.z)
         + lo2f(a.w)*lo2f(b.w) + hi2f(a.w)*hi2f(b.w);
}

// ---- per-array dtype flags: meta[30+id] = 0 bf16 / 1 fp32 / -1 unknown ----
__global__ void k_flags(const void* p0, const void* p1, const void* p2, const void* p3,
                        const void* p4, const void* p5, const void* p6, const void* p7,
                        const void* p8, const void* p9, const void* p10, const void* p11,
                        const void* p12,
                        int n0, int n1, int n2, int n3, int n4, int n5, int n6, int n7,
                        int n8, int n9, int n10, int n11, int n12,
                        int* __restrict__ meta)
{
    const void* ps[13] = {p0,p1,p2,p3,p4,p5,p6,p7,p8,p9,p10,p11,p12};
    int ns[13] = {n0,n1,n2,n3,n4,n5,n6,n7,n8,n9,n10,n11,n12};
    int id = blockIdx.x;
    const unsigned short* p = (const unsigned short*)ps[id];
    int half = ns[id] >> 1;
    int nsamp = (half < 256) ? half : 256;
    int step = (nsamp > 0) ? (half / nsamp) : 1;
    int tid = threadIdx.x;
    int sane = 0, nzv = 0;
    if (tid < nsamp){
        unsigned short u = p[2 * (tid * step)];
        nzv = (u != 0);
        int e = (u >> 7) & 0xFF;
        sane = (e >= 100 && e <= 140) ? 1 : 0;
    }
    __shared__ int c_s[4], c_n[4];
    unsigned long long ms = __ballot(sane != 0);
    unsigned long long mn = __ballot(nzv != 0);
    if ((tid & 63) == 0){ c_s[tid >> 6] = (int)__popcll(ms); c_n[tid >> 6] = (int)__popcll(mn); }
    __syncthreads();
    if (tid == 0){
        int cs = c_s[0] + c_s[1] + c_s[2] + c_s[3];
        int cn = c_n[0] + c_n[1] + c_n[2] + c_n[3];
        meta[30 + id] = (cn == 0) ? -1 : ((2 * cs >= nsamp) ? 0 : 1);
    }
}
__global__ void k_flagfix(int* meta){
    if (threadIdx.x == 0 && blockIdx.x == 0){
        int xf = meta[30]; if (xf < 0) xf = 1;
        meta[30] = xf; meta[24] = xf;
        for (int j = 1; j < 13; j++) if (meta[30 + j] < 0) meta[30 + j] = xf;
    }
}

// ---- identify src/dst/etype among the three E-sized int arrays ----
__global__ void k_trio(const int* pa, const int* pb, const int* pc, int E, int n,
                       int* __restrict__ meta){
    const int* ps[3] = {pa, pb, pc};
    int c = blockIdx.x, tid = threadIdx.x;
    const int* p = ps[c];
    int step = E / 1024; if (step < 1) step = 1;
    int mx = 0, hits = 0;
    for (int j = 0; j < 4; j++){
        long long e = (long long)(tid + j * 256) * step;
        if (e < E){
            int v = p[e];
            mx = max(mx, v);
            hits += (v == (int)(e % n)) ? 1 : 0;
        }
    }
    __shared__ int smx[4], sh[4];
    for (int o = 32; o; o >>= 1){ mx = max(mx, __shfl_down(mx, o, 64)); hits += __shfl_down(hits, o, 64); }
    if ((tid & 63) == 0){ smx[tid >> 6] = mx; sh[tid >> 6] = hits; }
    __syncthreads();
    if (tid == 0){
        mx = max(max(smx[0], smx[1]), max(smx[2], smx[3]));
        hits = sh[0] + sh[1] + sh[2] + sh[3];
        meta[44 + c] = mx; meta[47 + c] = hits;
    }
}
__global__ void k_pick(int* meta){
    if (threadIdx.x == 0 && blockIdx.x == 0){
        int m0 = meta[44], m1 = meta[45], m2 = meta[46];
        int h[3] = {meta[47], meta[48], meta[49]};
        int et = (m2 < 8) ? 2 : ((m0 < 8) ? 0 : ((m1 < 8) ? 1 : 2));
        int a = -1, b = -1;
        for (int c = 0; c < 3; c++) if (c != et){ if (a < 0) a = c; else b = c; }
        int srcsel = a, dstsel = b;
        if (h[a] >= 1000 && h[b] < 1000){ dstsel = a; srcsel = b; }
        meta[25] = srcsel; meta[26] = dstsel; meta[27] = et;
    }
}

// ---- fallbacks ----
__global__ void k_zerofill(float* out, int tot){
    int i = blockIdx.x * 256 + threadIdx.x;
    if (i < tot) out[i] = 0.f;
}
__global__ void k_copy(const void* __restrict__ xv, float* __restrict__ out,
                       const int* __restrict__ meta, int tot){
    int isf32 = meta[24];
    int i = blockIdx.x * 256 + threadIdx.x;
    if (i < tot) out[i] = ldf(xv, i, isf32);
}

// ---- bucket build (validated r3) ----
__global__ void k_init(int* meta){
    if (threadIdx.x < 24) meta[threadIdx.x] = 0;
}
__global__ void k_count(const int* __restrict__ nt, int* __restrict__ meta, int n){
    int i = blockIdx.x * 256 + threadIdx.x;
    int t = (i < n) ? (nt[i] & 3) : -1;
    int lane = threadIdx.x & 63;
    #pragma unroll
    for (int tt = 0; tt < TT; tt++){
        unsigned long long m = __ballot(t == tt);
        if (m){
            int leader = __builtin_ctzll(m);
            if (lane == leader) atomicAdd(&meta[tt], (int)__popcll(m));
        }
    }
}
__global__ void k_prefix(int* meta){
    if (threadIdx.x == 0){
        int off = 0, tb = 0;
        for (int t = 0; t < TT; t++){
            int c = meta[t];
            meta[4 + t]  = off;
            meta[13 + t] = off;
            meta[8 + t]  = tb;
            off += c;
            tb  += (c + 63) >> 6;
        }
        meta[12] = tb;
    }
}
__global__ void k_scatter(const int* __restrict__ nt, int* __restrict__ meta,
                          int* __restrict__ perm, int n){
    int i = blockIdx.x * 256 + threadIdx.x;
    int t = (i < n) ? (nt[i] & 3) : -1;
    int lane = threadIdx.x & 63;
    #pragma unroll
    for (int tt = 0; tt < TT; tt++){
        unsigned long long m = __ballot(t == tt);
        if (m){
            int leader = __builtin_ctzll(m);
            int base = 0;
            if (lane == leader) base = atomicAdd(&meta[13 + tt], (int)__popcll(m));
            base = __shfl(base, leader, 64);
            if (t == tt){
                int rank = __popcll(m & ((1ull << lane) - 1ull));
                perm[base + rank] = i;
            }
        }
    }
}

// ---- weight transpose: WT[m][outcol][k] = W[m][k][outcol] ----
__global__ void k_transW(const void* __restrict__ Wk, const void* __restrict__ Wq,
                         const void* __restrict__ Wv, const void* __restrict__ Wa,
                         unsigned short* __restrict__ WT, const int* __restrict__ meta)
{
    int idx = blockIdx.x * 256 + threadIdx.x;
    int m   = idx >> 16;
    int loc = idx & 65535;
    int j = loc >> 8, k = loc & 255;
    int mt = m >> 2, t = m & 3;
    const void* W = (mt == 0) ? Wk : (mt == 1) ? Wq : (mt == 2) ? Wv : Wa;
    int flag = meta[31 + mt];
    WT[idx] = f2us(ldf(W, t * 65536 + k * 256 + j, flag));
}

// ---- rel-table prep for MFMA path: hi/lo bf16 split; RMT transposed ----
// RAT[r][h][d][e] = rel_att[r][h][d][e]   (B layout [outcol=d][k=e])
// RMT[r][h][e][d] = rel_msg[r][h][d][e]   (B layout [outcol=e][k=d])
__global__ void k_transR(const void* __restrict__ rel_att, const void* __restrict__ rel_msg,
                         unsigned short* __restrict__ RATh, unsigned short* __restrict__ RATl,
                         unsigned short* __restrict__ RMTh, unsigned short* __restrict__ RMTl,
                         const int* __restrict__ meta)
{
    int idx = blockIdx.x * 256 + threadIdx.x;       // 0..65535
    int fra = meta[39], frm = meta[40];
    float wa = ldf(rel_att, idx, fra);
    unsigned short ha = f2us(wa);
    RATh[idx] = ha;
    RATl[idx] = f2us(wa - us2f(ha));
    int quad = idx >> 10, loc = idx & 1023, d = loc >> 5, e = loc & 31;
    float wm = ldf(rel_msg, quad * 1024 + d * 32 + e, frm);
    unsigned short hm = f2us(wm);
    int oidx = quad * 1024 + e * 32 + d;
    RMTh[oidx] = hm;
    RMTl[oidx] = f2us(wm - us2f(hm));
}

// ---- batched qt GEMM (B-reuse, bf16 out): qt[node-c0][r*256 + h*32 + d] =
//      sum_e q[node][h*32+e] * rel_att[r][h][d][e]  (hi/lo bf16 B)
//      wave w covers r in {2w,2w+1} x all 64 rows (4 tiles) ----
__global__ __launch_bounds__(256) void k_relq(
    const unsigned short* __restrict__ Ain,
    const unsigned short* __restrict__ Bhi, const unsigned short* __restrict__ Blo,
    unsigned short* __restrict__ outF, int c0, int cend)
{
    int base = c0 + blockIdx.x * 64;
    __shared__ __align__(16) unsigned short As[64 * 264];
    int tid = threadIdx.x;
    #pragma unroll
    for (int c = 0; c < 8; c++){
        int G = c * 256 + tid;            // granule of 8 halfs
        int row = G >> 5, g = G & 31;
        int node = base + row;
        uint4 v;
        if (node < cend) v = *reinterpret_cast<const uint4*>(Ain + (size_t)node * 256 + g * 8);
        else { v.x = v.y = v.z = v.w = 0u; }
        *reinterpret_cast<uint4*>(&As[row * 264 + g * 8]) = v;
    }
    __syncthreads();
    int wave = tid >> 6, lane = tid & 63;
    int m16 = lane & 15, quad = lane >> 4;

    #pragma unroll
    for (int rr = 0; rr < 2; rr++){
        int r = (wave << 1) + rr;
        #pragma unroll
        for (int h = 0; h < 8; h++){
            bf16x8 af[4];
            #pragma unroll
            for (int t = 0; t < 4; t++)
                af[t] = *reinterpret_cast<const bf16x8*>(&As[(t * 16 + m16) * 264 + h * 32 + quad * 8]);
            #pragma unroll
            for (int ct = 0; ct < 2; ct++){
                int bix = (((r * 8 + h) * 32) + ct * 16 + m16) * 32 + quad * 8;
                bf16x8 bh = *reinterpret_cast<const bf16x8*>(Bhi + bix);
                bf16x8 bl = *reinterpret_cast<const bf16x8*>(Blo + bix);
                floatx4 acr[4] = {};
                #pragma unroll
                for (int t = 0; t < 4; t++)
                    acr[t] = __builtin_amdgcn_mfma_f32_16x16x32_bf16(af[t], bl, acr[t], 0, 0, 0);
                #pragma unroll
                for (int t = 0; t < 4; t++)
                    acr[t] = __builtin_amdgcn_mfma_f32_16x16x32_bf16(af[t], bh, acr[t], 0, 0, 0);
                int colb = r * 256 + h * 32 + ct * 16 + m16;
                #pragma unroll
                for (int t = 0; t < 4; t++){
                    #pragma unroll
                    for (int reg = 0; reg < 4; reg++){
                        int node = base + t * 16 + quad * 4 + reg;
                        if (node < cend)
                            outF[(size_t)(node - c0) * 2048 + colb] = f2us(acr[t][reg]);
                    }
                }
            }
        }
    }
}

// ---- batched rel_msg GEMM (bf16 A, B hi/lo):
//      t[node][h*32+e] = sum_{r,d} M[node][r,h*32+d]*rel_msg[r,h,d,e]
//      wave w covers h in {2w,2w+1} x all 64 rows; acc persists across r ----
__global__ __launch_bounds__(256) void k_relmsg(
    const unsigned short* __restrict__ Mv,
    const unsigned short* __restrict__ Bhi, const unsigned short* __restrict__ Blo,
    unsigned short* __restrict__ outT, int c0, int cend)
{
    int base = c0 + blockIdx.x * 64;
    __shared__ __align__(16) unsigned short Ahi[64 * 264];
    int tid = threadIdx.x;
    int wave = tid >> 6, lane = tid & 63;
    int m16 = lane & 15, quad = lane >> 4;

    floatx4 acc[2][2][4] = {};   // [hh][ct][tile]

    for (int r = 0; r < RR; r++){
        __syncthreads();
        #pragma unroll
        for (int it = 0; it < 8; it++){
            int G = it * 256 + tid;       // granule of 8 halfs: 64 rows x 32 granules
            int row = G >> 5, g = G & 31;
            int node = base + row;
            uint4 vh;
            vh.x = vh.y = vh.z = vh.w = 0u;
            if (node < cend)
                vh = *reinterpret_cast<const uint4*>(Mv + (size_t)(node - c0) * 2048 + r * 256 + g * 8);
            *reinterpret_cast<uint4*>(&Ahi[row * 264 + g * 8]) = vh;
        }
        __syncthreads();
        #pragma unroll
        for (int hh = 0; hh < 2; hh++){
            int h = (wave << 1) + hh;
            bf16x8 ah[4];
            #pragma unroll
            for (int t = 0; t < 4; t++)
                ah[t] = *reinterpret_cast<const bf16x8*>(&Ahi[(t * 16 + m16) * 264 + h * 32 + quad * 8]);
            #pragma unroll
            for (int ct = 0; ct < 2; ct++){
                int bix = (((r * 8 + h) * 32) + ct * 16 + m16) * 32 + quad * 8;
                bf16x8 bh = *reinterpret_cast<const bf16x8*>(Bhi + bix);
                bf16x8 bl = *reinterpret_cast<const bf16x8*>(Blo + bix);
                #pragma unroll
                for (int t = 0; t < 4; t++){
                    acc[hh][ct][t] = __builtin_amdgcn_mfma_f32_16x16x32_bf16(ah[t], bh, acc[hh][ct][t], 0, 0, 0);
                    acc[hh][ct][t] = __builtin_amdgcn_mfma_f32_16x16x32_bf16(ah[t], bl, acc[hh][ct][t], 0, 0, 0);
                }
            }
        }
    }
    #pragma unroll
    for (int hh = 0; hh < 2; hh++){
        int h = (wave << 1) + hh;
        #pragma unroll
        for (int ct = 0; ct < 2; ct++){
            #pragma unroll
            for (int t = 0; t < 4; t++){
                #pragma unroll
                for (int reg = 0; reg < 4; reg++){
                    int node = base + t * 16 + quad * 4 + reg;
                    if (node < cend)
                        outT[(size_t)node * 256 + h * 32 + ct * 16 + m16] = f2us(acc[hh][ct][t][reg]);
                }
            }
        }
    }
}

// ---- CSR build ----
__global__ void k_zero(int* a, int n){
    int i = blockIdx.x * 256 + threadIdx.x;
    if (i < n) a[i] = 0;
}
__global__ void k_deg(const int* p2, const int* p3, const int* p4,
                      int* __restrict__ cnt, const int* __restrict__ meta, int E, int n){
    const int* dst = sel3(p2, p3, p4, meta[26]);
    int e = blockIdx.x * 256 + threadIdx.x;
    if (e < E){
        int d = dst[e];
        if (d >= 0 && d < n) atomicAdd(&cnt[d], 1);
    }
}
__global__ void k_scan1(const int* __restrict__ cnt, int* __restrict__ rowp,
                        int* __restrict__ bsum, int n){
    __shared__ int s[256];
    int b = blockIdx.x, tid = threadIdx.x;
    int i = b * 256 + tid;
    int v = (i < n) ? cnt[i] : 0;
    s[tid] = v;
    __syncthreads();
    for (int d = 1; d < 256; d <<= 1){
        int add = (tid >= d) ? s[tid - d] : 0;
        __syncthreads();
        s[tid] += add;
        __syncthreads();
    }
    if (i < n) rowp[i] = s[tid] - v;
    if (tid == 255) bsum[b] = s[255];
}
__global__ void k_scan2(int* bsum, int* rowp, int nb, int n){
    if (threadIdx.x == 0){
        int run = 0;
        for (int b = 0; b < nb; b++){ int t = bsum[b]; bsum[b] = run; run += t; }
        rowp[n] = run;
    }
}
__global__ void k_scan3(int* rowp, const int* __restrict__ bsum, int n){
    int i = blockIdx.x * 256 + threadIdx.x;
    if (i < n) rowp[i] += bsum[i >> 8];
}
__global__ void k_escat(const int* p2, const int* p3, const int* p4,
                        int* __restrict__ cur, const int* __restrict__ rowp,
                        int* __restrict__ eix, const int* __restrict__ meta, int E, int n){
    const int* dst = sel3(p2, p3, p4, meta[26]);
    int e = blockIdx.x * 256 + threadIdx.x;
    if (e < E){
        int d = dst[e];
        if (d >= 0 && d < n){
            int pos = atomicAdd(&cur[d], 1);
            eix[rowp[d] + pos] = e;
        }
    }
}

// ---- MFMA typed GEMM: QKV (validated r3, fp32-in adapted) ----
__global__ __launch_bounds__(256) void k_gemm_qkv(
    const void* __restrict__ Xv,
    const int* __restrict__ perm, const int* __restrict__ meta,
    const unsigned short* __restrict__ WT,
    const void* __restrict__ bk, const void* __restrict__ bq, const void* __restrict__ bv,
    unsigned short* __restrict__ kb, unsigned short* __restrict__ qb,
    unsigned short* __restrict__ vb)
{
    int rt = blockIdx.x;
    if (rt >= meta[12]) return;
    int fx = meta[30];
    int t = 0;
    while (t < TT - 1 && rt >= meta[8 + t + 1]) t++;
    int lt = rt - meta[8 + t];
    int rowStart = meta[4 + t] + (lt << 6);
    int rowEnd   = meta[4 + t] + meta[t];

    int ct = blockIdx.y;          // 0..5
    int mt = ct >> 1;             // 0=k 1=q 2=v
    int c0 = (ct & 1) * 128;
    const unsigned short* Wm = WT + (((mt << 2) + t) << 16);
    const void* bias = (mt == 0) ? bk : (mt == 1) ? bq : bv;
    int fb = meta[35 + mt];
    unsigned short* outb = (mt == 0) ? kb : (mt == 1) ? qb : vb;

    __shared__ __align__(16) unsigned short As[64 * 32];
    __shared__ __align__(16) unsigned short Bs[128 * 32];
    __shared__ int nodeIdx[64];

    int tid = threadIdx.x;
    if (tid < 64){
        int p = rowStart + tid;
        nodeIdx[tid] = perm[(p < rowEnd) ? p : (rowEnd - 1)];
    }
    __syncthreads();

    int wave = tid >> 6, lane = tid & 63;
    int wr = (wave >> 1) * 32;
    int wc = (wave & 1) * 64;
    int m16 = lane & 15, quad = lane >> 4;

    int arow = tid & 63, aseg = tid >> 6;
    int anode = nodeIdx[arow];

    floatx4 acc[2][4] = {};

    for (int k0 = 0; k0 < 256; k0 += 32){
        __syncthreads();
        uint4 av;
        if (fx){
            const float* af = (const float*)Xv + anode * 256 + aseg * 8 + k0;
            float4 f0 = *reinterpret_cast<const float4*>(af);
            float4 f1 = *reinterpret_cast<const float4*>(af + 4);
            av.x = (unsigned)f2us(f0.x) | ((unsigned)f2us(f0.y) << 16);
            av.y = (unsigned)f2us(f0.z) | ((unsigned)f2us(f0.w) << 16);
            av.z = (unsigned)f2us(f1.x) | ((unsigned)f2us(f1.y) << 16);
            av.w = (unsigned)f2us(f1.z) | ((unsigned)f2us(f1.w) << 16);
        } else {
            av = *reinterpret_cast<const uint4*>((const unsigned short*)Xv + anode * 256 + aseg * 8 + k0);
        }
        *reinterpret_cast<uint4*>(&As[sw32(arow, aseg)]) = av;
        #pragma unroll
        for (int it = 0; it < 2; it++){
            int idx2 = tid + it * 256;
            int cc = idx2 >> 2, g = idx2 & 3;
            uint4 bv4 = *reinterpret_cast<const uint4*>(Wm + (c0 + cc) * 256 + k0 + g * 8);
            *reinterpret_cast<uint4*>(&Bs[sw32(cc, g)]) = bv4;
        }
        __syncthreads();
        bf16x8 a[2], b[4];
        #pragma unroll
        for (int r = 0; r < 2; r++)
            a[r] = *reinterpret_cast<const bf16x8*>(&As[sw32(wr + r * 16 + m16, quad)]);
        #pragma unroll
        for (int c = 0; c < 4; c++)
            b[c] = *reinterpret_cast<const bf16x8*>(&Bs[sw32(wc + c * 16 + m16, quad)]);
        #pragma unroll
        for (int r = 0; r < 2; r++)
            #pragma unroll
            for (int c = 0; c < 4; c++)
                acc[r][c] = __builtin_amdgcn_mfma_f32_16x16x32_bf16(a[r], b[c], acc[r][c], 0, 0, 0);
    }

    #pragma unroll
    for (int r = 0; r < 2; r++){
        #pragma unroll
        for (int reg = 0; reg < 4; reg++){
            int row = wr + r * 16 + quad * 4 + reg;
            if (rowStart + row < rowEnd){
                int node = nodeIdx[row];
                #pragma unroll
                for (int c = 0; c < 4; c++){
                    int gc = c0 + wc + c * 16 + m16;
                    float v = acc[r][c][reg] + ldf(bias, t * 256 + gc, fb);
                    outb[node * 256 + gc] = f2us(v);
                }
            }
        }
    }
}

// ---- MFMA typed GEMM: output projection + skip gate (fp32 out) ----
__global__ __launch_bounds__(256) void k_gemm_out(
    const unsigned short* __restrict__ A,
    const void* __restrict__ Xv,
    const int* __restrict__ perm, const int* __restrict__ meta,
    const unsigned short* __restrict__ WTa,
    const void* __restrict__ ba, const void* __restrict__ skipv,
    float* __restrict__ out)
{
    int rt = blockIdx.x;
    if (rt >= meta[12]) return;
    int fx = meta[30], fba = meta[38], fsk = meta[42];
    int t = 0;
    while (t < TT - 1 && rt >= meta[8 + t + 1]) t++;
    int lt = rt - meta[8 + t];
    int rowStart = meta[4 + t] + (lt << 6);
    int rowEnd   = meta[4 + t] + meta[t];
    int c0 = blockIdx.y * 128;
    const unsigned short* Wm = WTa + (t << 16);
    float sg = ldf(skipv, t, fsk);
    float ag = 1.f / (1.f + __expf(-sg));

    __shared__ __align__(16) unsigned short As[64 * 32];
    __shared__ __align__(16) unsigned short Bs[128 * 32];
    __shared__ int nodeIdx[64];

    int tid = threadIdx.x;
    if (tid < 64){
        int p = rowStart + tid;
        nodeIdx[tid] = perm[(p < rowEnd) ? p : (rowEnd - 1)];
    }
    __syncthreads();

    int wave = tid >> 6, lane = tid & 63;
    int wr = (wave >> 1) * 32;
    int wc = (wave & 1) * 64;
    int m16 = lane & 15, quad = lane >> 4;

    int arow = tid & 63, aseg = tid >> 6;
    int anode = nodeIdx[arow];
    const unsigned short* aptr = A + anode * 256 + aseg * 8;

    floatx4 acc[2][4] = {};

    for (int k0 = 0; k0 < 256; k0 += 32){
        __syncthreads();
        uint4 av = *reinterpret_cast<const uint4*>(aptr + k0);
        *reinterpret_cast<uint4*>(&As[sw32(arow, aseg)]) = av;
        #pragma unroll
        for (int it = 0; it < 2; it++){
            int idx2 = tid + it * 256;
            int cc = idx2 >> 2, g = idx2 & 3;
            uint4 bv4 = *reinterpret_cast<const uint4*>(Wm + (c0 + cc) * 256 + k0 + g * 8);
            *reinterpret_cast<uint4*>(&Bs[sw32(cc, g)]) = bv4;
        }
        __syncthreads();
        bf16x8 a[2], b[4];
        #pragma unroll
        for (int r = 0; r < 2; r++)
            a[r] = *reinterpret_cast<const bf16x8*>(&As[sw32(wr + r * 16 + m16, quad)]);
        #pragma unroll
        for (int c = 0; c < 4; c++)
            b[c] = *reinterpret_cast<const bf16x8*>(&Bs[sw32(wc + c * 16 + m16, quad)]);
        #pragma unroll
        for (int r = 0; r < 2; r++)
            #pragma unroll
            for (int c = 0; c < 4; c++)
                acc[r][c] = __builtin_amdgcn_mfma_f32_16x16x32_bf16(a[r], b[c], acc[r][c], 0, 0, 0);
    }

    #pragma unroll
    for (int r = 0; r < 2; r++){
        #pragma unroll
        for (int reg = 0; reg < 4; reg++){
            int row = wr + r * 16 + quad * 4 + reg;
            if (rowStart + row < rowEnd){
                int node = nodeIdx[row];
                #pragma unroll
                for (int c = 0; c < 4; c++){
                    int gc = c0 + wc + c * 16 + m16;
                    float v = acc[r][c][reg] + ldf(ba, t * 256 + gc, fba);
                    float xv = ldf(Xv, node * 256 + gc, fx);
                    out[node * 256 + gc] = v * ag + xv * (1.f - ag);
                }
            }
        }
    }
}

// ---- VALU fallback projections (validated r7) ----
__global__ __launch_bounds__(256) void k_proj(
    const void* __restrict__ X, const int* __restrict__ nt,
    const void* __restrict__ Wk, const void* __restrict__ Wq, const void* __restrict__ Wv,
    const void* __restrict__ bk, const void* __restrict__ bq, const void* __restrict__ bv,
    unsigned short* __restrict__ kb, unsigned short* __restrict__ qtb,
    unsigned short* __restrict__ vb,
    const int* __restrict__ meta, int n)
{
    int i = blockIdx.x, tid = threadIdx.x;
    int fx = meta[30];
    int t = nt[i] & 3;
    __shared__ float xs[256];
    __shared__ float red[3][4][256];
    xs[tid] = ldf(X, i * 256 + tid, fx);
    __syncthreads();
    int seg = tid >> 6;
    int cg  = (tid & 63) * 4;
    int base = t * 65536 + cg;
    #pragma unroll
    for (int m = 0; m < 3; m++){
        const void* W = (m == 0) ? Wk : (m == 1) ? Wq : Wv;
        int fw = meta[31 + m];
        float ax = 0.f, ay = 0.f, az = 0.f, aw = 0.f;
        for (int k = seg * 64; k < seg * 64 + 64; k++){
            float xv = xs[k];
            float4 w = ldf4(W, base + k * 256, fw);
            ax += xv * w.x; ay += xv * w.y; az += xv * w.z; aw += xv * w.w;
        }
        float4 st = {ax, ay, az, aw};
        *reinterpret_cast<float4*>(&red[m][seg][cg]) = st;
    }
    __syncthreads();
    #pragma unroll
    for (int m = 0; m < 3; m++){
        const void* B = (m == 0) ? bk : (m == 1) ? bq : bv;
        unsigned short* O = (m == 0) ? kb : (m == 1) ? qtb : vb;
        float v = red[m][0][tid] + red[m][1][tid] + red[m][2][tid] + red[m][3][tid]
                + ldf(B, t * 256 + tid, meta[35 + m]);
        O[i * 256 + tid] = f2us(v);
    }
}
__global__ __launch_bounds__(256) void k_out(
    const unsigned short* __restrict__ tb,
    const void* __restrict__ X, const int* __restrict__ nt,
    const void* __restrict__ Wa, const void* __restrict__ ba,
    const void* __restrict__ skipv,
    float* __restrict__ out,
    const int* __restrict__ meta, int n)
{
    int i = blockIdx.x, tid = threadIdx.x;
    int fx = meta[30], fwa = meta[34], fba = meta[38], fsk = meta[42];
    int t = nt[i] & 3;
    __shared__ float xs[256];
    __shared__ float red[4][256];
    xs[tid] = us2f(tb[i * 256 + tid]);
    __syncthreads();
    int seg = tid >> 6;
    int cg  = (tid & 63) * 4;
    int base = t * 65536 + cg;
    float ax = 0.f, ay = 0.f, az = 0.f, aw = 0.f;
    for (int k = seg * 64; k < seg * 64 + 64; k++){
        float xv = xs[k];
        float4 w = ldf4(Wa, base + k * 256, fwa);
        ax += xv * w.x; ay += xv * w.y; az += xv * w.z; aw += xv * w.w;
    }
    float4 st = {ax, ay, az, aw};
    *reinterpret_cast<float4*>(&red[seg][cg]) = st;
    __syncthreads();
    float v = red[0][tid] + red[1][tid] + red[2][tid] + red[3][tid]
            + ldf(ba, t * 256 + tid, fba);
    float sg = ldf(skipv, t, fsk);
    float a  = 1.f / (1.f + __expf(-sg));
    float xv = ldf(X, i * 256 + tid, fx);
    out[i * 256 + tid] = v * a + xv * (1.f - a);
}

// ---- node attention + messages (fallback path, validated) ----
__global__ __launch_bounds__(256) void k_node2(
    unsigned short* qtb,
    const unsigned short* __restrict__ kb, const unsigned short* __restrict__ vb,
    const int* p2, const int* p3, const int* p4,
    const int* __restrict__ rowp, const int* __restrict__ eix,
    const void* __restrict__ rel_att, const void* __restrict__ rel_msg,
    const void* __restrict__ rel_pri,
    const int* __restrict__ meta, int n)
{
    const int* srcv = sel3(p2, p3, p4, meta[25]);
    const int* etv  = sel3(p2, p3, p4, meta[27]);
    int fra = meta[39], frm = meta[40], fpri = meta[41];
    int i = blockIdx.x, tid = threadIdx.x;
    int h5 = tid >> 5, z = tid & 31;

    __shared__ float qs[256];
    __shared__ float qA[RR * NH * 33];
    __shared__ float msum[RR][256];
    __shared__ float attS[16][NH];
    __shared__ float wnew[16][NH];
    __shared__ float mcur[RR][NH], dcur[RR][NH], scf[RR][NH];
    __shared__ int s_src[16], s_et[16];
    __shared__ float s_pri[RR * NH];
    __shared__ int s_mask;

    int e0 = rowp[i], deg = rowp[i + 1] - e0;

    if (tid < RR * NH) s_pri[tid] = ldf(rel_pri, tid, fpri);
    if (tid == 0) s_mask = 0;
    qs[tid] = us2f(qtb[i * 256 + tid]);
    #pragma unroll
    for (int r = 0; r < RR; r++) msum[r][tid] = 0.f;
    if (tid < RR * NH){ mcur[tid >> 3][tid & 7] = -1e30f; dcur[tid >> 3][tid & 7] = 0.f; }
    __syncthreads();

    {
        const float* qq = &qs[h5 * 32];
        #pragma unroll
        for (int r = 0; r < RR; r++){
            int base = (r * NH + h5) * 1024 + z * 32;
            float a0 = 0.f;
            #pragma unroll
            for (int e4 = 0; e4 < 8; e4++){
                float4 w = ldf4(rel_att, base + e4 * 4, fra);
                const float* q4 = qq + e4 * 4;
                a0 += w.x * q4[0] + w.y * q4[1] + w.z * q4[2] + w.w * q4[3];
            }
            qA[(r * NH + h5) * 33 + z] = a0;
        }
    }
    __syncthreads();

    for (int done = 0; done < deg; done += 16){
        int cs = min(16, deg - done);
        if (tid < cs){
            int e = eix[e0 + done + tid];
            int sj = srcv[e]; sj = (sj < 0) ? 0 : (sj >= n) ? n - 1 : sj;
            s_src[tid] = sj;
            int rr = etv[e] & 7;
            s_et[tid] = rr;
            atomicOr(&s_mask, 1 << rr);
        }
        __syncthreads();
        {
            int j = tid >> 4, hh = (tid >> 1) & 7, half = tid & 1;
            float pt = 0.f;
            if (j < cs){
                int sj = s_src[j], rj = s_et[j];
                const unsigned short* kp = kb + sj * 256 + hh * 32 + half * 16;
                const float* qa = &qA[(rj * NH + hh) * 33 + half * 16];
                uint4 u0 = *reinterpret_cast<const uint4*>(kp);
                uint4 u1 = *reinterpret_cast<const uint4*>(kp + 8);
                pt = lo2f(u0.x) * qa[0]  + hi2f(u0.x) * qa[1]
                   + lo2f(u0.y) * qa[2]  + hi2f(u0.y) * qa[3]
                   + lo2f(u0.z) * qa[4]  + hi2f(u0.z) * qa[5]
                   + lo2f(u0.w) * qa[6]  + hi2f(u0.w) * qa[7]
                   + lo2f(u1.x) * qa[8]  + hi2f(u1.x) * qa[9]
                   + lo2f(u1.y) * qa[10] + hi2f(u1.y) * qa[11]
                   + lo2f(u1.z) * qa[12] + hi2f(u1.z) * qa[13]
                   + lo2f(u1.w) * qa[14] + hi2f(u1.w) * qa[15];
            }
            pt += __shfl_xor(pt, 1);
            if (j < cs && half == 0)
                attS[j][hh] = pt * s_pri[s_et[j] * NH + hh] * 0.17677669529663687f;
        }
        __syncthreads();
        if (tid < RR * NH){
            int r = tid >> 3, hh = tid & 7;
            float m_old = mcur[r][hh];
            float m_new = m_old;
            for (int j = 0; j < cs; j++) if (s_et[j] == r) m_new = fmaxf(m_new, attS[j][hh]);
            float scale = __expf(m_old - m_new);
            float den = dcur[r][hh] * scale;
            for (int j = 0; j < cs; j++) if (s_et[j] == r) den += __expf(attS[j][hh] - m_new);
            mcur[r][hh] = m_new; dcur[r][hh] = den; scf[r][hh] = scale;
        }
        __syncthreads();
        #pragma unroll
        for (int r = 0; r < RR; r++) msum[r][tid] *= scf[r][h5];
        if (tid < cs * NH){
            int j = tid >> 3, hh = tid & 7;
            wnew[j][hh] = __expf(attS[j][hh] - mcur[s_et[j]][hh]);
        }
        __syncthreads();
        {
            float vvf[16];
            #pragma unroll
            for (int j = 0; j < 16; j++)
                if (j < cs) vvf[j] = us2f(vb[s_src[j] * 256 + tid]);
            for (int j = 0; j < cs; j++)
                msum[s_et[j]][tid] += wnew[j][h5] * vvf[j];
        }
        __syncthreads();
    }

    int mask = s_mask;
    #pragma unroll
    for (int r = 0; r < RR; r++){
        if ((mask >> r) & 1) msum[r][tid] /= dcur[r][h5];
    }
    __syncthreads();

    float tacc = 0.f;
    for (int r = 0; r < RR; r++){
        if (!((mask >> r) & 1)) continue;
        const float* ms = &msum[r][h5 * 32];
        int base = (r * NH + h5) * 1024 + z;
        float a0 = 0.f;
        #pragma unroll
        for (int c = 0; c < 32; c++)
            a0 += ms[c] * ldf(rel_msg, base + c * 32, frm);
        tacc += a0;
    }
    int np = __popc(mask); if (np == 0) np = 1;
    qtb[i * 256 + tid] = f2us(tacc / (float)np);
}

// ---- node attention, wave-per-node v2: no qA staging (direct global q reads),
//      output-ownership accumulate: lane l owns M[r=l>>3][h=l&7][d 0..31] ----
__global__ __launch_bounds__(64) void k_node6(
    const unsigned short* __restrict__ kb,
    const unsigned short* __restrict__ vb,
    unsigned short* __restrict__ qtM,
    const int* p2, const int* p3, const int* p4,
    const int* __restrict__ rowp, const int* __restrict__ eix,
    const void* __restrict__ rel_pri,
    const int* __restrict__ meta, int n, int c0)
{
    const int* srcv = sel3(p2, p3, p4, meta[25]);
    const int* etv  = sel3(p2, p3, p4, meta[27]);
    int fpri = meta[41];
    int i = c0 + blockIdx.x;
    int l = threadIdx.x;              // 0..63

    __shared__ float attS[16][NH];
    __shared__ float wnew[16][NH];
    __shared__ float mcur[RR][NH], dcur[RR][NH], scf[RR][NH];
    __shared__ int s_src[16], s_et[16];
    __shared__ float s_pri[RR * NH];
    __shared__ int s_mask;

    int e0 = rowp[i], deg = rowp[i + 1] - e0;

    s_pri[l] = ldf(rel_pri, l, fpri);
    if (l == 0) s_mask = 0;
    mcur[l >> 3][l & 7] = -1e30f;
    dcur[l >> 3][l & 7] = 0.f;

    const unsigned short* qrow = qtM + (size_t)blockIdx.x * 2048;  // [r][h][d] bf16
    int rl = l >> 3, hl = l & 7;      // this lane's output slice

    float racc[32];
    #pragma unroll
    for (int c = 0; c < 32; c++) racc[c] = 0.f;
    __syncthreads();

    for (int done = 0; done < deg; done += 16){
        int cs = min(16, deg - done);
        if (l < cs){
            int e = eix[e0 + done + l];
            int sj = srcv[e]; sj = (sj < 0) ? 0 : (sj >= n) ? n - 1 : sj;
            s_src[l] = sj;
            int rr = etv[e] & 7;
            s_et[l] = rr;
            atomicOr(&s_mask, 1 << rr);
        }
        __syncthreads();
        // dots: lane (j = l>>2, h2 = l&3) covers heads 2h2, 2h2+1; q read direct
        // from the L2-hot qt row (same bf16 values the LDS stage held before)
        {
            int j = l >> 2, h2 = l & 3;
            if (j < cs){
                int sj = s_src[j], rj = s_et[j];
                const unsigned short* kp = kb + (size_t)sj * 256 + h2 * 64;
                const unsigned short* qp = qrow + (rj * NH + 2 * h2) * 32;
                uint4 u0 = *reinterpret_cast<const uint4*>(kp);
                uint4 u1 = *reinterpret_cast<const uint4*>(kp + 8);
                uint4 u2 = *reinterpret_cast<const uint4*>(kp + 16);
                uint4 u3 = *reinterpret_cast<const uint4*>(kp + 24);
                uint4 u4 = *reinterpret_cast<const uint4*>(kp + 32);
                uint4 u5 = *reinterpret_cast<const uint4*>(kp + 40);
                uint4 u6 = *reinterpret_cast<const uint4*>(kp + 48);
                uint4 u7 = *reinterpret_cast<const uint4*>(kp + 56);
                uint4 q0 = *reinterpret_cast<const uint4*>(qp);
                uint4 q1 = *reinterpret_cast<const uint4*>(qp + 8);
                uint4 q2 = *reinterpret_cast<const uint4*>(qp + 16);
                uint4 q3 = *reinterpret_cast<const uint4*>(qp + 24);
                uint4 q4 = *reinterpret_cast<const uint4*>(qp + 32);
                uint4 q5 = *reinterpret_cast<const uint4*>(qp + 40);
                uint4 q6 = *reinterpret_cast<const uint4*>(qp + 48);
                uint4 q7 = *reinterpret_cast<const uint4*>(qp + 56);
                float pt0 = dbb(u0, q0) + dbb(u1, q1) + dbb(u2, q2) + dbb(u3, q3);
                float pt1 = dbb(u4, q4) + dbb(u5, q5) + dbb(u6, q6) + dbb(u7, q7);
                int pb = rj * NH + 2 * h2;
                attS[j][2 * h2]     = pt0 * s_pri[pb]     * 0.17677669529663687f;
                attS[j][2 * h2 + 1] = pt1 * s_pri[pb + 1] * 0.17677669529663687f;
            }
        }
        __syncthreads();
        // online softmax: lane = (r = l>>3, h = l&7), exactly 64 combos
        {
            int r = l >> 3, hh = l & 7;
            float m_old = mcur[r][hh];
            float m_new = m_old;
            for (int j = 0; j < cs; j++) if (s_et[j] == r) m_new = fmaxf(m_new, attS[j][hh]);
            float scale = __expf(m_old - m_new);
            float den = dcur[r][hh] * scale;
            for (int j = 0; j < cs; j++) if (s_et[j] == r) den += __expf(attS[j][hh] - m_new);
            mcur[r][hh] = m_new; dcur[r][hh] = den; scf[r][hh] = scale;
        }
        __syncthreads();
        // wnew: lane = (j = l>>2, h2 = l&3)
        {
            int j = l >> 2, h2 = l & 3;
            if (j < cs){
                int rj = s_et[j];
                wnew[j][2 * h2]     = __expf(attS[j][2 * h2]     - mcur[rj][2 * h2]);
                wnew[j][2 * h2 + 1] = __expf(attS[j][2 * h2 + 1] - mcur[rj][2 * h2 + 1]);
            }
        }
        // rescale this lane's slice (scf[rl][hl] valid from before this barrier-pair)
        {
            float sc = scf[rl][hl];
            #pragma unroll
            for (int c = 0; c < 32; c++) racc[c] *= sc;
        }
        __syncthreads();
        // accumulate: each edge feeds exactly one r; only lanes with rl==et work.
        // active 8 lanes read a coalesced 512B v-row slice (64B each)
        for (int j = 0; j < cs; j++){
            int et = s_et[j];
            if (rl == et){
                int sj = s_src[j];
                const unsigned short* vp = vb + (size_t)sj * 256 + hl * 32;
                uint4 v0 = *reinterpret_cast<const uint4*>(vp);
                uint4 v1 = *reinterpret_cast<const uint4*>(vp + 8);
                uint4 v2 = *reinterpret_cast<const uint4*>(vp + 16);
                uint4 v3 = *reinterpret_cast<const uint4*>(vp + 24);
                float w = wnew[j][hl];
                racc[0]  += w * lo2f(v0.x); racc[1]  += w * hi2f(v0.x);
                racc[2]  += w * lo2f(v0.y); racc[3]  += w * hi2f(v0.y);
                racc[4]  += w * lo2f(v0.z); racc[5]  += w * hi2f(v0.z);
                racc[6]  += w * lo2f(v0.w); racc[7]  += w * hi2f(v0.w);
                racc[8]  += w * lo2f(v1.x); racc[9]  += w * hi2f(v1.x);
                racc[10] += w * lo2f(v1.y); racc[11] += w * hi2f(v1.y);
                racc[12] += w * lo2f(v1.z); racc[13] += w * hi2f(v1.z);
                racc[14] += w * lo2f(v1.w); racc[15] += w * hi2f(v1.w);
                racc[16] += w * lo2f(v2.x); racc[17] += w * hi2f(v2.x);
                racc[18] += w * lo2f(v2.y); racc[19] += w * hi2f(v2.y);
                racc[20] += w * lo2f(v2.z); racc[21] += w * hi2f(v2.z);
                racc[22] += w * lo2f(v2.w); racc[23] += w * hi2f(v2.w);
                racc[24] += w * lo2f(v3.x); racc[25] += w * hi2f(v3.x);
                racc[26] += w * lo2f(v3.y); racc[27] += w * hi2f(v3.y);
                racc[28] += w * lo2f(v3.z); racc[29] += w * hi2f(v3.z);
                racc[30] += w * lo2f(v3.w); racc[31] += w * hi2f(v3.w);
            }
        }
        __syncthreads();
    }

    int mask = s_mask;
    int np = __popc(mask); if (np == 0) np = 1;
    float inv = 1.f / (float)np;
    // overwrite qt row with M = msum/den/np as one bf16 plane (row-local, safe)
    unsigned short* Mp = qtM + (size_t)blockIdx.x * 2048;
    float d = ((mask >> rl) & 1) ? (inv / dcur[rl][hl]) : 0.f;
    #pragma unroll
    for (int c4 = 0; c4 < 4; c4++){
        uint4 pk;
        pk.x = (unsigned)f2us(racc[c4*8+0] * d) | ((unsigned)f2us(racc[c4*8+1] * d) << 16);
        pk.y = (unsigned)f2us(racc[c4*8+2] * d) | ((unsigned)f2us(racc[c4*8+3] * d) << 16);
        pk.z = (unsigned)f2us(racc[c4*8+4] * d) | ((unsigned)f2us(racc[c4*8+5] * d) << 16);
        pk.w = (unsigned)f2us(racc[c4*8+6] * d) | ((unsigned)f2us(racc[c4*8+7] * d) << 16);
        *reinterpret_cast<uint4*>(Mp + rl * 256 + hl * 32 + c4 * 8) = pk;
    }
}

extern "C" void kernel_launch(void* const* d_in, const int* in_sizes, int n_in,
                              void* d_out, int out_size, void* d_ws, size_t ws_size,
                              hipStream_t stream)
{
    const void* x        = d_in[0];
    const int* node_type = (const int*)d_in[1];
    const int* p2        = (const int*)d_in[2];
    const int* p3        = (const int*)d_in[3];
    const int* p4        = (const int*)d_in[4];
    const void* Wk = d_in[5];  const void* bk = d_in[6];
    const void* Wq = d_in[7];  const void* bq = d_in[8];
    const void* Wv = d_in[9];  const void* bv = d_in[10];
    const void* Wa = d_in[11]; const void* ba = d_in[12];
    const void* rel_att = d_in[13];
    const void* rel_msg = d_in[14];
    const void* rel_pri = d_in[15];
    const void* skipv   = d_in[16];
    float* out = (float*)d_out;

    bool ok = (n_in == 17);
    if (ok){
        ok = ok && (in_sizes[0] == in_sizes[1] * 256);
        ok = ok && (in_sizes[2] == in_sizes[3]) && (in_sizes[3] == in_sizes[4]);
        ok = ok && (in_sizes[5] == 262144) && (in_sizes[7] == 262144)
                && (in_sizes[9] == 262144) && (in_sizes[11] == 262144);
        ok = ok && (in_sizes[6] == 1024) && (in_sizes[8] == 1024)
                && (in_sizes[10] == 1024) && (in_sizes[12] == 1024);
        ok = ok && (in_sizes[13] == 65536) && (in_sizes[14] == 65536);
        ok = ok && (in_sizes[15] == 64) && (in_sizes[16] == 4);
        ok = ok && (out_size == in_sizes[0]);
    }
    if (!ok){
        k_zerofill<<<(out_size + 255) / 256, 256, 0, stream>>>(out, out_size);
        return;
    }

    int n = in_sizes[1];
    int E = in_sizes[2];
    int nb = (n + 255) / 256;
    int eb = (E + 255) / 256;

    char* ws = (char*)d_ws;
    int* meta = (int*)ws;
    size_t off = 256;
    int* cnt  = (int*)(ws + off); off += ((size_t)n * 4 + 255) & ~(size_t)255;
    int* bsum = (int*)(ws + off); off += ((size_t)nb * 4 + 255) & ~(size_t)255;
    int* rowp = (int*)(ws + off); off += ((size_t)(n + 1) * 4 + 255) & ~(size_t)255;
    int* eix  = (int*)(ws + off); off += ((size_t)E * 4 + 255) & ~(size_t)255;
    unsigned short* kb2 = (unsigned short*)(ws + off); off += (size_t)n * 256 * 2;
    unsigned short* vb2 = (unsigned short*)(ws + off); off += (size_t)n * 256 * 2;
    unsigned short* qtb = (unsigned short*)(ws + off); off += (size_t)n * 256 * 2;
    size_t off_lean = off;
    int* perm = (int*)(ws + off); off += ((size_t)n * 4 + 255) & ~(size_t)255;
    unsigned short* WT = (unsigned short*)(ws + off); off += (size_t)16 * 65536 * 2;
    size_t off_full = off;
    // ---- rel-transform tables (hi/lo bf16) + adaptive chunk buffer (bf16 rows) ----
    unsigned short* RATh = (unsigned short*)(ws + off); off += (size_t)65536 * 2;
    unsigned short* RATl = (unsigned short*)(ws + off); off += (size_t)65536 * 2;
    unsigned short* RMTh = (unsigned short*)(ws + off); off += (size_t)65536 * 2;
    unsigned short* RMTl = (unsigned short*)(ws + off); off += (size_t)65536 * 2;
    unsigned short* qtM = (unsigned short*)(ws + off);   // C * 4096 bytes
    size_t avail = (ws_size > off) ? ws_size - off : 0;
    long long Cavail = (long long)(avail / 4096);
    if (Cavail > (long long)n) Cavail = n;
    int C = 0;
    if (Cavail >= 1024){
        // target ~32K nodes/chunk (~128 MB qt+M stream); balance chunk sizes
        int target = 32768;
        int nch = (n + target - 1) / target;
        int Ceven = ((n + nch - 1) / nch + 63) & ~(int)63;
        C = (Ceven < (int)Cavail) ? Ceven : (int)Cavail;
    }

    k_flags<<<13, 256, 0, stream>>>(x, Wk, Wq, Wv, Wa, bk, bq, bv, ba,
                                    rel_att, rel_msg, rel_pri, skipv,
                                    in_sizes[0], in_sizes[5], in_sizes[7], in_sizes[9],
                                    in_sizes[11], in_sizes[6], in_sizes[8], in_sizes[10],
                                    in_sizes[12], in_sizes[13], in_sizes[14],
                                    in_sizes[15], in_sizes[16], meta);
    k_flagfix<<<1, 64, 0, stream>>>(meta);

    if (ws_size < off_lean){
        k_copy<<<(n * 256 + 255) / 256, 256, 0, stream>>>(x, out, meta, n * 256);
        return;
    }
    bool full  = (ws_size >= off_full);
    bool full2 = full && (C >= 1024);

    k_trio<<<3, 256, 0, stream>>>(p2, p3, p4, E, n, meta);
    k_pick<<<1, 64, 0, stream>>>(meta);

    // CSR
    k_zero<<<nb, 256, 0, stream>>>(cnt, n);
    k_deg<<<eb, 256, 0, stream>>>(p2, p3, p4, cnt, meta, E, n);
    k_scan1<<<nb, 256, 0, stream>>>(cnt, rowp, bsum, n);
    k_scan2<<<1, 64, 0, stream>>>(bsum, rowp, nb, n);
    k_scan3<<<nb, 256, 0, stream>>>(rowp, bsum, n);
    k_zero<<<nb, 256, 0, stream>>>(cnt, n);
    k_escat<<<eb, 256, 0, stream>>>(p2, p3, p4, cnt, rowp, eix, meta, E, n);

    if (full){
        k_init<<<1, 64, 0, stream>>>(meta);
        k_count<<<nb, 256, 0, stream>>>(node_type, meta, n);
        k_prefix<<<1, 64, 0, stream>>>(meta);
        k_scatter<<<nb, 256, 0, stream>>>(node_type, meta, perm, n);
        k_transW<<<4096, 256, 0, stream>>>(Wk, Wq, Wv, Wa, WT, meta);
        int maxRT = n / 64 + TT;
        k_gemm_qkv<<<dim3(maxRT, 6), 256, 0, stream>>>(x, perm, meta, WT, bk, bq, bv,
                                                       kb2, qtb, vb2);
        if (full2){
            k_transR<<<256, 256, 0, stream>>>(rel_att, rel_msg, RATh, RATl, RMTh, RMTl, meta);
            for (int c0 = 0; c0 < n; c0 += C){
                int cend = (c0 + C < n) ? (c0 + C) : n;
                int blk64 = (cend - c0 + 63) >> 6;
                k_relq<<<blk64, 256, 0, stream>>>(qtb, RATh, RATl, qtM, c0, cend);
                k_node6<<<cend - c0, 64, 0, stream>>>(kb2, vb2, qtM, p2, p3, p4,
                                                      rowp, eix, rel_pri, meta, n, c0);
                k_relmsg<<<blk64, 256, 0, stream>>>(qtM, RMTh, RMTl, qtb, c0, cend);
            }
        } else {
            k_node2<<<n, 256, 0, stream>>>(qtb, kb2, vb2, p2, p3, p4, rowp, eix,
                                           rel_att, rel_msg, rel_pri, meta, n);
        }
        k_gemm_out<<<dim3(maxRT, 2), 256, 0, stream>>>(qtb, x, perm, meta,
                                                       WT + 12 * 65536, ba, skipv, out);
    } else {
        k_proj<<<n, 256, 0, stream>>>(x, node_type, Wk, Wq, Wv, bk, bq, bv,
                                      kb2, qtb, vb2, meta, n);
        k_node2<<<n, 256, 0, stream>>>(qtb, kb2, vb2, p2, p3, p4, rowp, eix,
                                       rel_att, rel_msg, rel_pri, meta, n);
        k_out<<<n, 256, 0, stream>>>(qtb, x, node_type, Wa, ba, skipv, out, meta, n);
    }
}